// Round 2
// baseline (932.196 us; speedup 1.0000x reference)
//
#include <hip/hip_runtime.h>

#define N_SRC    100000
#define N_NODES  1000000
#define N_NEIGH  20
#define DRAW     256
#define DH       128
#define DMSG     128
#define DNEI     128
#define LDS_PAD  8   // +8 bf16 = 16B: keeps 16B alignment, breaks 16-way bank conflict

typedef __bf16 bf16x8 __attribute__((ext_vector_type(8)));
typedef float  floatx4 __attribute__((ext_vector_type(4)));
typedef unsigned int uint32;

// ---------------- ws layout (fast path) ----------------
// W1t @0 (64KB) | W2t @64K (32KB) | Wnt @96K (32KB) | h @1MB (25.6MB bf16)
// agg @32MB (25.6MB bf16) | membf @64MB (244.1MB bf16)  => need 320MB
#define OFF_W1T   (0ull)
#define OFF_W2T   (64ull * 1024)
#define OFF_WNT   (96ull * 1024)
#define OFF_H     (1ull << 20)
#define OFF_AGG   (32ull << 20)
#define OFF_MEMBF (64ull << 20)
#define WS_NEED   (320ull << 20)

// K2 geometry: interleave 3 gemm1-blocks : 4 convert-blocks per period of 7
#define G1_BLOCKS   1563                   // ceil(N_SRC/64)
#define K2_PERIODS  521                    // ceil(1563/3)
#define K2_TOTAL    (K2_PERIODS * 7)       // 3647
#define CV_BLOCKS   (K2_PERIODS * 4)       // 2084
#define NCHUNK      ((size_t)N_NODES * DNEI / 8)   // 16,000,000 bf16x8 chunks

// ---- kernel 1: cast weights to bf16, transposed to [n][k] so each MFMA
// B-fragment (n = lane&15 fixed, k = quad*8..+8 contiguous) is one 16B load.
__global__ void convert_weights(const float* __restrict__ W1,
                                const float* __restrict__ W2,
                                const float* __restrict__ Wn,
                                __bf16* __restrict__ W1t,
                                __bf16* __restrict__ W2t,
                                __bf16* __restrict__ Wnt) {
    int i = blockIdx.x * 256 + threadIdx.x;           // 0..65535
    if (i < 32768) {                                  // W1t[n][k], n<128, k<256
        int n = i >> 8, k = i & 255;
        W1t[i] = (__bf16)W1[k * 128 + n];
    } else if (i < 49152) {                           // W2t[n][k], 128x128
        int j = i - 32768;
        int n = j >> 7, k = j & 127;
        W2t[j] = (__bf16)W2[k * 128 + n];
    } else {                                          // Wnt[n][k], 128x128
        int j = i - 49152;
        int n = j >> 7, k = j & 127;
        Wnt[j] = (__bf16)Wn[k * 128 + n];
    }
}

// ---- kernel 2 (fast path): block-specialized.
//   convert-blocks: memory fp32 -> bf16 (nontemporal fp32 reads; bf16 array
//                   is 244MB ~= L3, stays resident for the gather kernel)
//   gemm1-blocks:   h = relu(raw @ W1 + b1) -> h (bf16, global ws)
// The two types are independent; co-residency overlaps the 768MB sequential
// convert traffic with GEMM1's compute.
__global__ __launch_bounds__(256)
void convert_and_gemm1(const float* __restrict__ raw,
                       const float* __restrict__ memv,
                       const float* __restrict__ b1,
                       const __bf16* __restrict__ W1t,
                       __bf16* __restrict__ membf,
                       __bf16* __restrict__ h) {
    __shared__ __bf16 hbuf[64][DH + LDS_PAD];

    const int bid = blockIdx.x;
    const int tid = threadIdx.x;
    const int r   = bid % 7;
    const int p   = bid / 7;

    if (r >= 3) {
        // -------- convert block --------
        const int cvid = p * 4 + (r - 3);              // 0..2083
        size_t c = (size_t)cvid * 256 + tid;
        const size_t stride = (size_t)CV_BLOCKS * 256;
        for (; c < NCHUNK; c += stride) {
            const floatx4* src = reinterpret_cast<const floatx4*>(memv + c * 8);
            floatx4 a = __builtin_nontemporal_load(src);
            floatx4 b = __builtin_nontemporal_load(src + 1);
            bf16x8 o;
            o[0]=(__bf16)a[0]; o[1]=(__bf16)a[1]; o[2]=(__bf16)a[2]; o[3]=(__bf16)a[3];
            o[4]=(__bf16)b[0]; o[5]=(__bf16)b[1]; o[6]=(__bf16)b[2]; o[7]=(__bf16)b[3];
            *reinterpret_cast<bf16x8*>(membf + c * 8) = o;
        }
        return;
    }

    // -------- gemm1 block --------
    const int g1id = p * 3 + r;                        // 0..1562 exactly
    const int s0   = g1id * 64;
    const int lane = tid & 63;
    const int wave = tid >> 6;
    const int mr   = lane & 15;
    const int quad = lane >> 4;

    {
        int rowg = s0 + wave * 16 + mr;
        int rowc = rowg < N_SRC ? rowg : N_SRC - 1;    // clamp; masked at store
        const float* ar = raw + (size_t)rowc * DRAW;

        floatx4 acc[8];
        #pragma unroll
        for (int nt = 0; nt < 8; ++nt) { floatx4 z = {0.f,0.f,0.f,0.f}; acc[nt] = z; }

        #pragma unroll
        for (int kk = 0; kk < DRAW; kk += 32) {
            const int kb = kk + quad * 8;
            floatx4 a0 = __builtin_nontemporal_load(
                reinterpret_cast<const floatx4*>(ar + kb));
            floatx4 a1 = __builtin_nontemporal_load(
                reinterpret_cast<const floatx4*>(ar + kb) + 1);
            bf16x8 af;
            af[0]=(__bf16)a0[0]; af[1]=(__bf16)a0[1]; af[2]=(__bf16)a0[2]; af[3]=(__bf16)a0[3];
            af[4]=(__bf16)a1[0]; af[5]=(__bf16)a1[1]; af[6]=(__bf16)a1[2]; af[7]=(__bf16)a1[3];
            #pragma unroll
            for (int nt = 0; nt < 8; ++nt) {
                bf16x8 bf = *reinterpret_cast<const bf16x8*>(
                    W1t + (nt * 16 + mr) * DRAW + kb);
                acc[nt] = __builtin_amdgcn_mfma_f32_16x16x32_bf16(af, bf, acc[nt], 0, 0, 0);
            }
        }
        // epilogue: +b1, relu -> hbuf (C/D layout: col=lane&15, row=quad*4+r)
        #pragma unroll
        for (int nt = 0; nt < 8; ++nt) {
            const int col  = nt * 16 + mr;
            const float bias = b1[col];
            #pragma unroll
            for (int rr = 0; rr < 4; ++rr) {
                int mrow = wave * 16 + quad * 4 + rr;
                float v = acc[nt][rr] + bias;
                hbuf[mrow][col] = (__bf16)(v > 0.f ? v : 0.f);
            }
        }
    }

    __syncthreads();

    // coalesced copy hbuf -> h[s0..s0+64)
    const int cr = tid >> 4;            // 0..15
    const int cc = (tid & 15) * 8;      // 0..120
    #pragma unroll
    for (int it = 0; it < 4; ++it) {
        int row = cr + it * 16;
        int rg  = s0 + row;
        if (rg < N_SRC) {
            *reinterpret_cast<bf16x8*>(h + (size_t)rg * DH + cc) =
                *reinterpret_cast<const bf16x8*>(&hbuf[row][cc]);
        }
    }
}

// ---- kernel 3 (fast path): gather + mean-pool over bf16 memory.
// One 64-lane wave per source; 20 independent 256B row loads in flight.
// membf is ~L3-resident after kernel 2 -> duplicate touches are L3 hits.
__global__ __launch_bounds__(256)
void gather_bf16(const int*    __restrict__ neigh,
                 const __bf16* __restrict__ membf,
                 __bf16*       __restrict__ aggb) {
    int wid0 = blockIdx.x * 4 + (threadIdx.x >> 6);
    const int wid  = __builtin_amdgcn_readfirstlane(wid0);  // force SGPR: idx reads become s_loads
    const int lane = threadIdx.x & 63;
    if (wid >= N_SRC) return;

    const int* nb = neigh + wid * N_NEIGH;
    uint32 v[N_NEIGH];
    #pragma unroll
    for (int n = 0; n < N_NEIGH; ++n) {
        int idx = nb[n];                                    // wave-uniform -> s_load
        v[n] = *reinterpret_cast<const uint32*>(
            membf + (size_t)idx * DNEI + lane * 2);         // 64 lanes x 4B = 256B row
    }
    float sx = 0.f, sy = 0.f;
    #pragma unroll
    for (int n = 0; n < N_NEIGH; ++n) {
        sx += __builtin_bit_cast(float, v[n] << 16);
        sy += __builtin_bit_cast(float, v[n] & 0xffff0000u);
    }
    const float inv = 1.0f / N_NEIGH;
    __bf16 r0 = (__bf16)(sx * inv);
    __bf16 r1 = (__bf16)(sy * inv);
    union { __bf16 b[2]; uint32 u; } pk;
    pk.b[0] = r0; pk.b[1] = r1;
    *reinterpret_cast<uint32*>(aggb + (size_t)wid * DNEI + lane * 2) = pk.u;
}

// ---- kernel 4 (fast path): GEMM2 (h@W2) + GEMM3 (agg@Wn), fused epilogue.
// h/agg fragments read directly from global bf16 (L2/L3-hot, 16B/lane loads).
__global__ __launch_bounds__(256)
void gemm23(const __bf16* __restrict__ h,
            const __bf16* __restrict__ aggb,
            const float*  __restrict__ b2,
            const float*  __restrict__ bn,
            const __bf16* __restrict__ W2t,
            const __bf16* __restrict__ Wnt,
            float* __restrict__ out) {
    const int tid  = threadIdx.x;
    const int s0   = blockIdx.x * 64;
    const int lane = tid & 63;
    const int wave = tid >> 6;
    const int mr   = lane & 15;
    const int quad = lane >> 4;

    const int rowg = s0 + wave * 16 + mr;
    const int rowc = rowg < N_SRC ? rowg : N_SRC - 1;

    bf16x8 af2[4], af3[4];
    #pragma unroll
    for (int i = 0; i < 4; ++i) {
        const int kb = i * 32 + quad * 8;
        af2[i] = *reinterpret_cast<const bf16x8*>(h    + (size_t)rowc * DH   + kb);
        af3[i] = *reinterpret_cast<const bf16x8*>(aggb + (size_t)rowc * DNEI + kb);
    }

    floatx4 acc2[8], acc3[8];
    #pragma unroll
    for (int nt = 0; nt < 8; ++nt) {
        floatx4 z = {0.f,0.f,0.f,0.f}; acc2[nt] = z; acc3[nt] = z;
    }

    #pragma unroll
    for (int i = 0; i < 4; ++i) {
        const int kb = i * 32 + quad * 8;
        #pragma unroll
        for (int nt = 0; nt < 8; ++nt) {
            bf16x8 bw2 = *reinterpret_cast<const bf16x8*>(
                W2t + (nt * 16 + mr) * DH + kb);
            acc2[nt] = __builtin_amdgcn_mfma_f32_16x16x32_bf16(af2[i], bw2, acc2[nt], 0, 0, 0);
            bf16x8 bw3 = *reinterpret_cast<const bf16x8*>(
                Wnt + (nt * 16 + mr) * DNEI + kb);
            acc3[nt] = __builtin_amdgcn_mfma_f32_16x16x32_bf16(af3[i], bw3, acc3[nt], 0, 0, 0);
        }
    }

    #pragma unroll
    for (int nt = 0; nt < 8; ++nt) {
        const int col = nt * 16 + mr;
        const float bb2 = b2[col];
        const float bbn = bn[col];
        #pragma unroll
        for (int rr = 0; rr < 4; ++rr) {
            int rowl = wave * 16 + quad * 4 + rr;
            int rg   = s0 + rowl;
            if (rg < N_SRC) {
                float va = acc2[nt][rr] + bb2; va = va > 0.f ? va : 0.f;
                float vb = acc3[nt][rr] + bbn; vb = vb > 0.f ? vb : 0.f;
                out[(size_t)rg * DMSG + col] = va + vb;
            }
        }
    }
}

// ================= fallback path (verified round-1 kernels) =================
__global__ __launch_bounds__(256)
void gather_mean(const int*   __restrict__ neigh,
                 const float* __restrict__ memv,
                 float*       __restrict__ agg) {
    const int wid  = blockIdx.x * 4 + (threadIdx.x >> 6);
    const int lane = threadIdx.x & 63;
    if (wid >= N_SRC) return;

    int myidx = 0;
    if (lane < N_NEIGH) myidx = neigh[wid * N_NEIGH + lane];

    float2 v[N_NEIGH];
    #pragma unroll
    for (int n = 0; n < N_NEIGH; ++n) {
        int idx = __shfl(myidx, n, 64);
        v[n] = reinterpret_cast<const float2*>(memv + (size_t)idx * DNEI)[lane];
    }
    float sx = 0.f, sy = 0.f;
    #pragma unroll
    for (int n = 0; n < N_NEIGH; ++n) { sx += v[n].x; sy += v[n].y; }
    const float inv = 1.0f / N_NEIGH;
    float2 rr; rr.x = sx * inv; rr.y = sy * inv;
    reinterpret_cast<float2*>(agg + (size_t)wid * DNEI)[lane] = rr;
}

__global__ __launch_bounds__(256)
void mlp_kernel(const float* __restrict__ raw,
                const float* __restrict__ agg,     // aliases out
                const float* __restrict__ b1,
                const float* __restrict__ b2,
                const float* __restrict__ bn,
                const __bf16* __restrict__ W1t,
                const __bf16* __restrict__ W2t,
                const __bf16* __restrict__ Wnt,
                float* __restrict__ out) {
    __shared__ __bf16 hbuf[64][DH + LDS_PAD];

    const int tid  = threadIdx.x;
    const int s0   = blockIdx.x * 64;
    const int lane = tid & 63;
    const int wave = tid >> 6;
    const int mr   = lane & 15;
    const int quad = lane >> 4;

    const int rowg = s0 + wave * 16 + mr;
    const int rowc = rowg < N_SRC ? rowg : N_SRC - 1;

    float4 ag[8];
    {
        const float* ar3 = agg + (size_t)rowc * DNEI;
        #pragma unroll
        for (int i = 0; i < 4; ++i) {
            ag[2 * i]     = *reinterpret_cast<const float4*>(ar3 + i * 32 + quad * 8);
            ag[2 * i + 1] = *reinterpret_cast<const float4*>(ar3 + i * 32 + quad * 8 + 4);
        }
    }

    {
        const float* ar = raw + (size_t)rowc * DRAW;
        floatx4 acc[8];
        #pragma unroll
        for (int nt = 0; nt < 8; ++nt) { floatx4 z = {0.f,0.f,0.f,0.f}; acc[nt] = z; }

        #pragma unroll
        for (int kk = 0; kk < DRAW; kk += 32) {
            const int kb = kk + quad * 8;
            float4 a0 = *reinterpret_cast<const float4*>(ar + kb);
            float4 a1 = *reinterpret_cast<const float4*>(ar + kb + 4);
            bf16x8 af;
            af[0]=(__bf16)a0.x; af[1]=(__bf16)a0.y; af[2]=(__bf16)a0.z; af[3]=(__bf16)a0.w;
            af[4]=(__bf16)a1.x; af[5]=(__bf16)a1.y; af[6]=(__bf16)a1.z; af[7]=(__bf16)a1.w;
            #pragma unroll
            for (int nt = 0; nt < 8; ++nt) {
                bf16x8 bf = *reinterpret_cast<const bf16x8*>(
                    W1t + (nt * 16 + mr) * DRAW + kb);
                acc[nt] = __builtin_amdgcn_mfma_f32_16x16x32_bf16(af, bf, acc[nt], 0, 0, 0);
            }
        }
        #pragma unroll
        for (int nt = 0; nt < 8; ++nt) {
            const int col  = nt * 16 + mr;
            const float bias = b1[col];
            #pragma unroll
            for (int rr = 0; rr < 4; ++rr) {
                int mrow = wave * 16 + quad * 4 + rr;
                float v = acc[nt][rr] + bias;
                hbuf[mrow][col] = (__bf16)(v > 0.f ? v : 0.f);
            }
        }
    }

    __syncthreads();

    {
        floatx4 acc2[8], acc3[8];
        #pragma unroll
        for (int nt = 0; nt < 8; ++nt) {
            floatx4 z = {0.f,0.f,0.f,0.f}; acc2[nt] = z; acc3[nt] = z;
        }

        #pragma unroll
        for (int kk = 0; kk < DH; kk += 32) {
            const int kb = kk + quad * 8;
            const int i  = kk >> 5;
            bf16x8 af2 = *reinterpret_cast<const bf16x8*>(&hbuf[wave * 16 + mr][kb]);
            bf16x8 af3;
            {
                float4 g0 = ag[2 * i], g1 = ag[2 * i + 1];
                af3[0]=(__bf16)g0.x; af3[1]=(__bf16)g0.y; af3[2]=(__bf16)g0.z; af3[3]=(__bf16)g0.w;
                af3[4]=(__bf16)g1.x; af3[5]=(__bf16)g1.y; af3[6]=(__bf16)g1.z; af3[7]=(__bf16)g1.w;
            }
            #pragma unroll
            for (int nt = 0; nt < 8; ++nt) {
                bf16x8 bw2 = *reinterpret_cast<const bf16x8*>(
                    W2t + (nt * 16 + mr) * DH + kb);
                acc2[nt] = __builtin_amdgcn_mfma_f32_16x16x32_bf16(af2, bw2, acc2[nt], 0, 0, 0);
                bf16x8 bw3 = *reinterpret_cast<const bf16x8*>(
                    Wnt + (nt * 16 + mr) * DNEI + kb);
                acc3[nt] = __builtin_amdgcn_mfma_f32_16x16x32_bf16(af3, bw3, acc3[nt], 0, 0, 0);
            }
        }

        #pragma unroll
        for (int nt = 0; nt < 8; ++nt) {
            const int col = nt * 16 + mr;
            const float bb2 = b2[col];
            const float bbn = bn[col];
            #pragma unroll
            for (int rr = 0; rr < 4; ++rr) {
                int rowl = wave * 16 + quad * 4 + rr;
                int rg   = s0 + rowl;
                if (rg < N_SRC) {
                    float va = acc2[nt][rr] + bb2; va = va > 0.f ? va : 0.f;
                    float vb = acc3[nt][rr] + bbn; vb = vb > 0.f ? vb : 0.f;
                    out[(size_t)rg * DMSG + col] = va + vb;
                }
            }
        }
    }
}

extern "C" void kernel_launch(void* const* d_in, const int* in_sizes, int n_in,
                              void* d_out, int out_size, void* d_ws, size_t ws_size,
                              hipStream_t stream) {
    const float* raw   = (const float*)d_in[0];
    const int*   neigh = (const int*)  d_in[1];
    const float* memv  = (const float*)d_in[2];
    const float* W1    = (const float*)d_in[3];
    const float* b1    = (const float*)d_in[4];
    const float* W2    = (const float*)d_in[5];
    const float* b2    = (const float*)d_in[6];
    const float* Wn    = (const float*)d_in[7];
    const float* bn    = (const float*)d_in[8];
    float* out = (float*)d_out;

    __bf16* W1t = (__bf16*)((char*)d_ws + OFF_W1T);
    __bf16* W2t = (__bf16*)((char*)d_ws + OFF_W2T);
    __bf16* Wnt = (__bf16*)((char*)d_ws + OFF_WNT);

    convert_weights<<<dim3(256), dim3(256), 0, stream>>>(W1, W2, Wn, W1t, W2t, Wnt);

    if (ws_size >= WS_NEED) {
        __bf16* h     = (__bf16*)((char*)d_ws + OFF_H);
        __bf16* aggb  = (__bf16*)((char*)d_ws + OFF_AGG);
        __bf16* membf = (__bf16*)((char*)d_ws + OFF_MEMBF);

        convert_and_gemm1<<<dim3(K2_TOTAL), dim3(256), 0, stream>>>(
            raw, memv, b1, W1t, membf, h);
        gather_bf16<<<dim3((N_SRC + 3) / 4), dim3(256), 0, stream>>>(
            neigh, membf, aggb);
        gemm23<<<dim3(G1_BLOCKS), dim3(256), 0, stream>>>(
            h, aggb, b2, bn, W2t, Wnt, out);
    } else {
        // fallback: verified round-1 path (fp32 gather staged in `out`)
        float* agg = out;
        gather_mean<<<dim3((N_SRC + 3) / 4), dim3(256), 0, stream>>>(neigh, memv, agg);
        mlp_kernel<<<dim3(G1_BLOCKS), dim3(256), 0, stream>>>(
            raw, agg, b1, b2, bn, W1t, W2t, Wnt, out);
    }
}